// Round 5
// baseline (358.673 us; speedup 1.0000x reference)
//
#include <hip/hip_runtime.h>
#include <hip/hip_bf16.h>

// NLinear: out[b,f,o] = sum_i x[b,f,i] * w[f,i,o] + bias[f,o]
// B=8192, F=64, I=128, O=128, fp32. ~540MB min traffic -> ~86us floor.
//
// R5: latency-bound fix. 512-thr blocks (8 waves x 16 rows), grid 512
// (natural order: f = b&63 -> XCD k keeps features k mod 8 L2-resident AND
// concurrent blocks cover all 64 slices of the same rows -> full DRAM lines
// consumed). W^T bf16 LDS staged once per 1024 rows. X loads double-buffered
// across tiles (2-deep reg pipeline, ~16 outstanding dwordx4/wave). No
// barriers in the main loop.

#define NF 64
#define DI 128
#define DO 128
#define WROWS 16
#define WAVES 8
#define BMT (WROWS * WAVES)          // 128 rows per block-tile
#define TILES 8
#define ROWSPB (BMT * TILES)         // 1024 rows per block
#define RS (NF * DI)                 // 8192 floats: row stride of x and out

typedef __attribute__((ext_vector_type(8))) short short8;
typedef __attribute__((ext_vector_type(4))) float floatx4;

// round-to-nearest-even f32 -> bf16 bits
static __device__ __forceinline__ unsigned short f2bf(float f) {
    union { float f; unsigned u; } v; v.f = f;
    unsigned r = v.u + 0x7fffu + ((v.u >> 16) & 1u);
    return (unsigned short)(r >> 16);
}

__global__ __launch_bounds__(512, 4)
void nlinear_kernel(const float* __restrict__ x,
                    const float* __restrict__ w,
                    const float* __restrict__ bias,
                    float* __restrict__ out) {
    // W^T bf16, swizzled: element (o,i) at byte o*256 + ((i*2) ^ ((o&15)<<4)).
    __shared__ unsigned short lds_wt[DO * DI];   // 32 KB
    __shared__ float lds_bias[DO];               // 512 B

    int b = blockIdx.x;
    int f = b & 63;                // feature: fastest -> row-sharing + XCD residency
    int q = b >> 6;                // 0..7: row band
    int tid  = threadIdx.x;
    int lane = tid & 63;
    int wid  = tid >> 6;           // 0..7
    int lrow = lane & 15;          // batch-row sub-index / o sub-index
    int kq   = lane >> 4;          // k-quarter 0..3

    // ---- stage W^T (coalesced float4 reads, bf16 swizzled scatter writes) ----
    const float* wf = w + (size_t)f * DI * DO;
    #pragma unroll
    for (int it = 0; it < 8; ++it) {
        int id = it * 512 + tid;
        int i  = id >> 5;              // k index 0..127
        int o4 = (id & 31) << 2;       // output-col group
        floatx4 v = *(const floatx4*)(wf + i * DO + o4);
        #pragma unroll
        for (int j = 0; j < 4; ++j) {
            int o = o4 + j;
            int byte = o * 256 + ((i * 2) ^ ((o & 15) << 4));
            *(unsigned short*)((char*)lds_wt + byte) = f2bf(v[j]);
        }
    }
    if (tid < DO) lds_bias[tid] = bias[f * DO + tid];
    __syncthreads();   // the only barrier; LDS read-only below

    // per-lane base pointers (this wave's lrow-th row of tile 0)
    size_t row0 = (size_t)q * ROWSPB + wid * WROWS + lrow;
    const float* xw = x   + row0 * RS + f * DI + kq * 8;
    float*       ow = out + row0 * RS + f * DO + kq * 4;

    floatx4 rawA[8], rawB[8];

    auto load_tile = [&](floatx4* r, int t) {
        const float* p = xw + (size_t)t * BMT * RS;
        #pragma unroll
        for (int kk = 0; kk < 4; ++kk)
            #pragma unroll
            for (int h = 0; h < 2; ++h)
                r[kk * 2 + h] = *(const floatx4*)(p + kk * 32 + h * 4);
    };

    auto compute_store = [&](const floatx4* r, int t) {
        floatx4 acc[8];
        #pragma unroll
        for (int n = 0; n < 8; ++n)   // lrow-uniform -> LDS broadcast (free)
            acc[n] = *(const floatx4*)(lds_bias + n * 16 + kq * 4);
        #pragma unroll
        for (int kk = 0; kk < 4; ++kk) {
            floatx4 v0 = r[kk * 2], v1 = r[kk * 2 + 1];
            short8 a;
            a[0] = (short)f2bf(v0[0]); a[1] = (short)f2bf(v0[1]);
            a[2] = (short)f2bf(v0[2]); a[3] = (short)f2bf(v0[3]);
            a[4] = (short)f2bf(v1[0]); a[5] = (short)f2bf(v1[1]);
            a[6] = (short)f2bf(v1[2]); a[7] = (short)f2bf(v1[3]);
            int kb = (kk * 64 + kq * 16) ^ (lrow << 4);
            #pragma unroll
            for (int n = 0; n < 8; ++n) {
                short8 bw = *(const short8*)((const char*)lds_wt
                              + (n * 16 + lrow) * 256 + kb);
                acc[n] = __builtin_amdgcn_mfma_f32_16x16x32_bf16(
                             bw, a, acc[n], 0, 0, 0);
            }
        }
        float* op = ow + (size_t)t * BMT * RS;
        #pragma unroll
        for (int n = 0; n < 8; ++n)
            *(floatx4*)(op + n * 16) = acc[n];
    };

    // ---- 2-deep cross-tile pipeline: tile t+1/t+2 loads fly under tile t ----
    load_tile(rawA, 0);
    load_tile(rawB, 1);
    #pragma unroll 1
    for (int t = 0; t < TILES - 2; t += 2) {
        compute_store(rawA, t);
        load_tile(rawA, t + 2);
        compute_store(rawB, t + 1);
        if (t + 3 < TILES) load_tile(rawB, t + 3);
    }
    compute_store(rawA, TILES - 2);
    compute_store(rawB, TILES - 1);
}

extern "C" void kernel_launch(void* const* d_in, const int* in_sizes, int n_in,
                              void* d_out, int out_size, void* d_ws, size_t ws_size,
                              hipStream_t stream) {
    const float* x    = (const float*)d_in[0];
    const float* wght = (const float*)d_in[1];
    const float* bias = (const float*)d_in[2];
    float* out        = (float*)d_out;

    dim3 grid(NF * 8);    // 512 blocks: 8 row-bands x 64 features
    dim3 block(512);
    nlinear_kernel<<<grid, block, 0, stream>>>(x, wght, bias, out);
}

// Round 6
// 160.098 us; speedup vs baseline: 2.2403x; 2.2403x over previous
//
#include <hip/hip_runtime.h>
#include <hip/hip_bf16.h>

// NLinear: out[b,f,o] = sum_i x[b,f,i] * w[f,i,o] + bias[f,o]
// B=8192, F=64, I=128, O=128, fp32. ~540MB min traffic -> ~86us floor.
//
// R6: asm-enforced load pipeline. R2/R3/R5 proved the compiler sinks C++-level
// batched loads (VGPR pinned 52-64). Here the 8 x-tile loads are a single
// asm volatile block (outputs force-allocated), with counted s_waitcnt vmcnt(8)
// so tile t+1's loads stay in flight across tile t's whole compute phase.
// W^T bf16 in LDS (33KB), 4 blocks/CU x 4 waves. Feature-major XCD map
// (R1/R4's 134MB FETCH). No barriers in the main loop.

#define NF 64
#define DI 128
#define DO 128
#define WROWS 16
#define WAVES 4
#define BMT (WROWS * WAVES)      // 64 rows per block-tile
#define TILES 8
#define ROWSPB (BMT * TILES)     // 512 rows per block
#define CHUNKS 16                // 8192 / 512
#define RS (NF * DI)             // 8192 floats

typedef __attribute__((ext_vector_type(8))) short short8;
typedef __attribute__((ext_vector_type(4))) float floatx4;

// round-to-nearest-even f32 -> bf16 bits
static __device__ __forceinline__ unsigned short f2bf(float f) {
    union { float f; unsigned u; } v; v.f = f;
    unsigned r = v.u + 0x7fffu + ((v.u >> 16) & 1u);
    return (unsigned short)(r >> 16);
}

// 8 batched dwordx4 loads the scheduler cannot split or sink.
// offsets (bytes): kk*128 + h*16 for kk=0..3, h=0..1
#define ISSUE8(r, p)                                                     \
    asm volatile(                                                        \
        "global_load_dwordx4 %0, %8, off\n\t"                            \
        "global_load_dwordx4 %1, %8, off offset:16\n\t"                  \
        "global_load_dwordx4 %2, %8, off offset:128\n\t"                 \
        "global_load_dwordx4 %3, %8, off offset:144\n\t"                 \
        "global_load_dwordx4 %4, %8, off offset:256\n\t"                 \
        "global_load_dwordx4 %5, %8, off offset:272\n\t"                 \
        "global_load_dwordx4 %6, %8, off offset:384\n\t"                 \
        "global_load_dwordx4 %7, %8, off offset:400\n\t"                 \
        : "=&v"(r[0]), "=&v"(r[1]), "=&v"(r[2]), "=&v"(r[3]),            \
          "=&v"(r[4]), "=&v"(r[5]), "=&v"(r[6]), "=&v"(r[7])             \
        : "v"(p) : "memory")

__global__ __launch_bounds__(256, 4)
void nlinear_kernel(const float* __restrict__ x,
                    const float* __restrict__ w,
                    const float* __restrict__ bias,
                    float* __restrict__ out) {
    // W^T bf16, swizzled: element (o,i) at byte o*256 + ((i*2) ^ ((o&15)<<4)).
    __shared__ unsigned short lds_wt[DO * DI];   // 32 KB
    __shared__ float lds_bias[DO];

    // Feature-major XCD swizzle: 8 features/XCD, W_f L2-resident,
    // same-feature blocks contiguous (keeps x L3-friendly: R1/R4 FETCH=134MB).
    int b = blockIdx.x;
    int logical = (b & 7) * (NF * CHUNKS / 8) + (b >> 3);
    int f = logical >> 4;          // 0..63
    int chunk = logical & 15;      // 0..15

    int tid  = threadIdx.x;
    int lane = tid & 63;
    int wid  = tid >> 6;           // 0..3
    int lrow = lane & 15;
    int kq   = lane >> 4;          // 0..3

    size_t row0 = (size_t)chunk * ROWSPB + wid * WROWS + lrow;
    const float* xw = x   + row0 * RS + f * DI + kq * 8;
    float*       ow = out + row0 * RS + f * DO + kq * 4;

    floatx4 raw[8];
    ISSUE8(raw, xw);               // tile 0 flies under W staging

    // ---- stage W^T: paired rows -> ds_write_b32 (halves write count) ----
    const float* wf = w + (size_t)f * DI * DO;
    #pragma unroll
    for (int it = 0; it < 8; ++it) {
        int id = it * 256 + tid;
        int o4 = (id & 31) << 2;
        int i  = (id >> 5) * 2;            // even row
        floatx4 v0 = *(const floatx4*)(wf + i * DO + o4);
        floatx4 v1 = *(const floatx4*)(wf + (i + 1) * DO + o4);
        #pragma unroll
        for (int j = 0; j < 4; ++j) {
            int o = o4 + j;
            int byte = o * 256 + ((i * 2) ^ ((o & 15) << 4));
            unsigned pk = (unsigned)f2bf(v0[j]) | ((unsigned)f2bf(v1[j]) << 16);
            *(unsigned*)((char*)lds_wt + byte) = pk;
        }
    }
    if (tid < DO) lds_bias[tid] = bias[f * DO + tid];
    __syncthreads();   // drains vmcnt(0): raw(tile0) also ready

    short8 ax[4];
    #pragma unroll
    for (int kk = 0; kk < 4; ++kk) {       // convert tile 0
        floatx4 v0 = raw[kk * 2], v1 = raw[kk * 2 + 1];
        short8 a;
        a[0] = (short)f2bf(v0[0]); a[1] = (short)f2bf(v0[1]);
        a[2] = (short)f2bf(v0[2]); a[3] = (short)f2bf(v0[3]);
        a[4] = (short)f2bf(v1[0]); a[5] = (short)f2bf(v1[1]);
        a[6] = (short)f2bf(v1[2]); a[7] = (short)f2bf(v1[3]);
        ax[kk] = a;
    }
    ISSUE8(raw, xw + (size_t)BMT * RS);    // tile 1 in flight

    #pragma unroll
    for (int t = 0; t < TILES; ++t) {
        // ---- compute tile t from ax (no memory dependency) ----
        floatx4 acc[8];
        #pragma unroll
        for (int n = 0; n < 8; ++n)
            acc[n] = *(const floatx4*)(lds_bias + n * 16 + kq * 4);
        #pragma unroll
        for (int kk = 0; kk < 4; ++kk) {
            int kb = (kk * 64 + kq * 16) ^ (lrow << 4);
            #pragma unroll
            for (int n = 0; n < 8; ++n) {
                short8 bw = *(const short8*)((const char*)lds_wt
                              + (n * 16 + lrow) * 256 + kb);
                acc[n] = __builtin_amdgcn_mfma_f32_16x16x32_bf16(
                             bw, ax[kk], acc[n], 0, 0, 0);
            }
        }
        float* op = ow + (size_t)t * BMT * RS;
        #pragma unroll
        for (int n = 0; n < 8; ++n)
            *(floatx4*)(op + n * 16) = acc[n];

        if (t < TILES - 1) {
            // outstanding: [loads(t+1) oldest, stores(t) newest] (+ older
            // stores already forced out by the previous wait). vmcnt(8)
            // retires loads(t+1) + stale stores, leaves stores(t) in flight.
            asm volatile("s_waitcnt vmcnt(8)" ::: "memory");
            __builtin_amdgcn_sched_barrier(0);
            #pragma unroll
            for (int kk = 0; kk < 4; ++kk) {   // convert tile t+1
                floatx4 v0 = raw[kk * 2], v1 = raw[kk * 2 + 1];
                short8 a;
                a[0] = (short)f2bf(v0[0]); a[1] = (short)f2bf(v0[1]);
                a[2] = (short)f2bf(v0[2]); a[3] = (short)f2bf(v0[3]);
                a[4] = (short)f2bf(v1[0]); a[5] = (short)f2bf(v1[1]);
                a[6] = (short)f2bf(v1[2]); a[7] = (short)f2bf(v1[3]);
                ax[kk] = a;
            }
            if (t < TILES - 2)
                ISSUE8(raw, xw + (size_t)(t + 2) * BMT * RS);
        }
    }
}

extern "C" void kernel_launch(void* const* d_in, const int* in_sizes, int n_in,
                              void* d_out, int out_size, void* d_ws, size_t ws_size,
                              hipStream_t stream) {
    const float* x    = (const float*)d_in[0];
    const float* wght = (const float*)d_in[1];
    const float* bias = (const float*)d_in[2];
    float* out        = (float*)d_out;

    dim3 grid(NF * CHUNKS);   // 1024
    dim3 block(256);
    nlinear_kernel<<<grid, block, 0, stream>>>(x, wght, bias, out);
}